// Round 10
// baseline (332.824 us; speedup 1.0000x reference)
//
#include <hip/hip_runtime.h>
#include <hip/hip_bf16.h>

typedef __bf16 bf16_t;
typedef __bf16 bf16x8 __attribute__((ext_vector_type(8)));
typedef float f32x4 __attribute__((ext_vector_type(4)));

__device__ __forceinline__ unsigned short f32_to_bf16_rn(float f) {
  unsigned u = __float_as_uint(f);
  u += 0x7fffu + ((u >> 16) & 1u);
  return (unsigned short)(u >> 16);
}

__device__ __forceinline__ float gelu_exact(float x) {
  return 0.5f * x * (1.0f + erff(x * 0.7071067811865475f));
}

#define GLDS16(g, l)                                                          \
  __builtin_amdgcn_global_load_lds(                                           \
      (const __attribute__((address_space(1))) void*)(g),                     \
      (__attribute__((address_space(3))) void*)(l), 16, 0, 0)

// ---------------- cast x -> bf16 ----------------
__global__ void cast_x_kernel(const float* __restrict__ in,
                              unsigned short* __restrict__ out, int n4) {
  int i = blockIdx.x * blockDim.x + threadIdx.x;
  if (i >= n4) return;
  float4 v = ((const float4*)in)[i];
  ushort4 o;
  o.x = f32_to_bf16_rn(v.x);
  o.y = f32_to_bf16_rn(v.y);
  o.z = f32_to_bf16_rn(v.z);
  o.w = f32_to_bf16_rn(v.w);
  ((ushort4*)out)[i] = o;
}

// ---------------- build compacted index list (deterministic scan) ----------
__global__ void build_idx_kernel(const float* __restrict__ mask1,
                                 const float* __restrict__ mask2,
                                 int* __restrict__ idx, int* __restrict__ meta,
                                 int H, int D) {
  __shared__ int sums[1024];
  const int t = threadIdx.x;
  int flags[8];
  int tot = 0;
#pragma unroll
  for (int u = 0; u < 8; ++u) {
    int j = t * 8 + u;
    int f = (mask1[(long long)j * D] != 0.0f) && (mask2[j] != 0.0f);
    flags[u] = f;
    tot += f;
  }
  sums[t] = tot;
  __syncthreads();
  for (int off = 1; off < 1024; off <<= 1) {
    int v = (t >= off) ? sums[t - off] : 0;
    __syncthreads();
    sums[t] += v;
    __syncthreads();
  }
  int pos = sums[t] - tot;
#pragma unroll
  for (int u = 0; u < 8; ++u) {
    if (flags[u]) idx[pos++] = t * 8 + u;
  }
  if (t == 1023) {
    int count = sums[1023];
    meta[0] = count;
    meta[1] = (count + 127) & ~127;  // kpad, multiple of 128 (so ncol even)
  }
}

// ---------------- compact + cast w1 rows ----------------
__global__ void compact_w1_kernel(const float* __restrict__ w1,
                                  const int* __restrict__ idx,
                                  const int* __restrict__ meta,
                                  unsigned short* __restrict__ w1c, int D) {
  int q = blockIdx.x * blockDim.x + threadIdx.x;
  int k = q >> 9;
  int d4 = (q & 511) << 2;
  int count = meta[0];
  ushort4 o = {0, 0, 0, 0};
  if (k < count) {
    int j = idx[k];
    float4 v = *(const float4*)(w1 + (long long)j * D + d4);
    o.x = f32_to_bf16_rn(v.x);
    o.y = f32_to_bf16_rn(v.y);
    o.z = f32_to_bf16_rn(v.z);
    o.w = f32_to_bf16_rn(v.w);
  }
  *(ushort4*)(w1c + (long long)k * D + d4) = o;
}

// ---------------- compact + cast w2 cols (ld 4096) ----------------
__global__ void compact_w2_kernel(const float* __restrict__ w2,
                                  const int* __restrict__ idx,
                                  const int* __restrict__ meta,
                                  unsigned short* __restrict__ w2c, int H) {
  int q = blockIdx.x * blockDim.x + threadIdx.x;
  int n = q >> 10;
  int k4 = (q & 1023) << 2;
  int count = meta[0];
  ushort4 o = {0, 0, 0, 0};
  const float* src = w2 + (long long)n * H;
#pragma unroll
  for (int u = 0; u < 4; ++u) {
    int k = k4 + u;
    unsigned short v = 0;
    if (k < count) v = f32_to_bf16_rn(src[idx[k]]);
    ((unsigned short*)&o)[u] = v;
  }
  *(ushort4*)(w2c + (long long)n * 4096 + k4) = o;
}

// =========== 128x64-tile pool GEMM: TLP-saturation design ===================
// C[M,N]=A[M,K]*B[N,K]^T. 4 waves (2x2), per-wave 64x32 out, BK=32.
// SINGLE-buffered 12KB LDS (R1's proven structure: stage->sync->read->mfma->
// sync; per-wave stalls hidden by ~24 resident waves/CU, m114 TLP).
// Pool of 2048 blocks grid-strides a virtual (row=tau&63, col=tau>>6) tile
// space sized on-device (ncol from meta) -> every block live.
// Col-major tau: XCD = bid%8 = row%8 -> 8 A-panels/XCD (~4MB) L2-resident,
// B-panels reused 8x back-to-back.
template <int EPI>
__global__ __launch_bounds__(256, 4) void gemm_pool_kernel(
    const bf16_t* __restrict__ A, const bf16_t* __restrict__ B,
    void* __restrict__ Cout, long long ldA, long long ldB, long long ldC,
    int Kfix, int ncolFix, const int* __restrict__ meta) {
  const int kpad = meta[1];
  const int K = (EPI == 0) ? kpad : Kfix;       // GEMM2: K dynamic
  const int ncol = (EPI == 1) ? (kpad >> 6) : ncolFix;  // GEMM1: cols dynamic
  const int ntiles = ncol << 6;                 // nrow = 64

  __shared__ bf16_t As[128 * 32];  // 8KB
  __shared__ bf16_t Bs[64 * 32];   // 4KB

  const int tid = threadIdx.x;
  const int l = tid & 63;
  const int w = tid >> 6;
  const int wm = w >> 1;  // 0..1 : 64-row half
  const int wn = w & 1;   // 0..1 : 32-col half

  const int srow = tid >> 2;        // 0..63
  const int c0 = (tid & 3) * 8;     // staging col elems
  bf16_t* Al0 = &As[tid * 8];
  bf16_t* Al1 = &As[2048 + tid * 8];
  bf16_t* Bl0 = &Bs[tid * 8];

  const int fr = l & 15;
  const int fc = (l >> 4) * 8;

  for (int tau = blockIdx.x; tau < ntiles; tau += gridDim.x) {
    const int row = tau & 63;
    const int col = tau >> 6;
    const long long brow = (long long)row * 128;
    const long long bcol = (long long)col * 64;

    const bf16_t* Ag0 = A + (brow + srow) * ldA + c0;
    const bf16_t* Ag1 = A + (brow + 64 + srow) * ldA + c0;
    const bf16_t* Bg0 = B + (bcol + srow) * ldB + c0;

    f32x4 acc[4][2];
#pragma unroll
    for (int m = 0; m < 4; ++m)
#pragma unroll
      for (int n = 0; n < 2; ++n) acc[m][n] = (f32x4){0.f, 0.f, 0.f, 0.f};

    for (int k0 = 0; k0 < K; k0 += 32) {
      GLDS16(Ag0 + k0, Al0);
      GLDS16(Ag1 + k0, Al1);
      GLDS16(Bg0 + k0, Bl0);
      __syncthreads();
      bf16x8 af[4], bfr[2];
#pragma unroll
      for (int m = 0; m < 4; ++m)
        af[m] = *(const bf16x8*)(&As[(wm * 64 + m * 16 + fr) * 32 + fc]);
#pragma unroll
      for (int n = 0; n < 2; ++n)
        bfr[n] = *(const bf16x8*)(&Bs[(wn * 32 + n * 16 + fr) * 32 + fc]);
#pragma unroll
      for (int m = 0; m < 4; ++m)
#pragma unroll
        for (int n = 0; n < 2; ++n)
          acc[m][n] = __builtin_amdgcn_mfma_f32_16x16x32_bf16(
              af[m], bfr[n], acc[m][n], 0, 0, 0);
      __syncthreads();
    }

    const int orow = wm * 64 + (l >> 4) * 4;
    const int ocol = wn * 32 + (l & 15);
#pragma unroll
    for (int m = 0; m < 4; ++m)
#pragma unroll
      for (int n = 0; n < 2; ++n)
#pragma unroll
        for (int r = 0; r < 4; ++r) {
          long long rr = brow + orow + m * 16 + r;
          long long cc = bcol + ocol + n * 16;
          float v = acc[m][n][r];
          if (EPI == 1) {
            ((unsigned short*)Cout)[rr * ldC + cc] =
                f32_to_bf16_rn(gelu_exact(v));
          } else {
            ((float*)Cout)[rr * ldC + cc] = v;
          }
        }
  }
}

extern "C" void kernel_launch(void* const* d_in, const int* in_sizes, int n_in,
                              void* d_out, int out_size, void* d_ws,
                              size_t ws_size, hipStream_t stream) {
  const float* x = (const float*)d_in[0];
  const float* w1 = (const float*)d_in[1];
  const float* w2 = (const float*)d_in[2];
  const float* mask1 = (const float*)d_in[3];
  const float* mask2 = (const float*)d_in[4];
  float* out = (float*)d_out;

  const int D = 2048, H = 8192, M = 8192;
  const int KP = 4096;

  char* ws = (char*)d_ws;
  unsigned short* xb = (unsigned short*)ws;
  unsigned short* w1c = xb + (size_t)M * D;
  unsigned short* w2c = w1c + (size_t)KP * D;
  unsigned short* hb = w2c + (size_t)D * KP;
  int* idx = (int*)(hb + (size_t)M * KP);
  int* meta = idx + KP;

  build_idx_kernel<<<1, 1024, 0, stream>>>(mask1, mask2, idx, meta, H, D);

  {
    int n4 = (M * D) / 4;
    cast_x_kernel<<<n4 / 256, 256, 0, stream>>>(x, xb, n4);
  }
  {
    int nq = KP * (D / 4);
    compact_w1_kernel<<<nq / 256, 256, 0, stream>>>(w1, idx, meta, w1c, D);
  }
  {
    int nq = D * (KP / 4);
    compact_w2_kernel<<<nq / 256, 256, 0, stream>>>(w2, idx, meta, w2c, H);
  }

  const int POOL = 2048;  // 8 blocks/CU launched; ~6 resident (LDS/VGPR)

  // GEMM1: h[:, 0:kpad] = gelu(x @ w1c^T). K=2048 fixed, ncol = kpad/64 (dev)
  gemm_pool_kernel<1><<<POOL, 256, 0, stream>>>(
      (const bf16_t*)xb, (const bf16_t*)w1c, hb, (long long)D, (long long)D,
      (long long)KP, D, 0, meta);

  // GEMM2: out = h @ w2c^T. K = kpad (dev), ncol = 2048/64 = 32 fixed
  gemm_pool_kernel<0><<<POOL, 256, 0, stream>>>(
      (const bf16_t*)hb, (const bf16_t*)w2c, out, (long long)KP,
      (long long)KP, (long long)D, 0, 32, meta);
}

// Round 11
// 267.007 us; speedup vs baseline: 1.2465x; 1.2465x over previous
//
#include <hip/hip_runtime.h>
#include <hip/hip_bf16.h>

typedef __bf16 bf16_t;
typedef __bf16 bf16x8 __attribute__((ext_vector_type(8)));
typedef float f32x4 __attribute__((ext_vector_type(4)));

__device__ __forceinline__ unsigned short f32_to_bf16_rn(float f) {
  unsigned u = __float_as_uint(f);
  u += 0x7fffu + ((u >> 16) & 1u);
  return (unsigned short)(u >> 16);
}

__device__ __forceinline__ float gelu_exact(float x) {
  return 0.5f * x * (1.0f + erff(x * 0.7071067811865475f));
}

#define GLDS16(g, l)                                                          \
  __builtin_amdgcn_global_load_lds(                                           \
      (const __attribute__((address_space(1))) void*)(g),                     \
      (__attribute__((address_space(3))) void*)(l), 16, 0, 0)

// ---------------- cast x -> bf16 ----------------
__global__ void cast_x_kernel(const float* __restrict__ in,
                              unsigned short* __restrict__ out, int n4) {
  int i = blockIdx.x * blockDim.x + threadIdx.x;
  if (i >= n4) return;
  float4 v = ((const float4*)in)[i];
  ushort4 o;
  o.x = f32_to_bf16_rn(v.x);
  o.y = f32_to_bf16_rn(v.y);
  o.z = f32_to_bf16_rn(v.z);
  o.w = f32_to_bf16_rn(v.w);
  ((ushort4*)out)[i] = o;
}

// ---------------- build compacted index list (deterministic scan) ----------
__global__ void build_idx_kernel(const float* __restrict__ mask1,
                                 const float* __restrict__ mask2,
                                 int* __restrict__ idx, int* __restrict__ meta,
                                 int H, int D) {
  __shared__ int sums[1024];
  const int t = threadIdx.x;
  int flags[8];
  int tot = 0;
#pragma unroll
  for (int u = 0; u < 8; ++u) {
    int j = t * 8 + u;
    int f = (mask1[(long long)j * D] != 0.0f) && (mask2[j] != 0.0f);
    flags[u] = f;
    tot += f;
  }
  sums[t] = tot;
  __syncthreads();
  for (int off = 1; off < 1024; off <<= 1) {
    int v = (t >= off) ? sums[t - off] : 0;
    __syncthreads();
    sums[t] += v;
    __syncthreads();
  }
  int pos = sums[t] - tot;
#pragma unroll
  for (int u = 0; u < 8; ++u) {
    if (flags[u]) idx[pos++] = t * 8 + u;
  }
  if (t == 1023) {
    int count = sums[1023];
    meta[0] = count;
    meta[1] = (count + 127) & ~127;  // kpad: multiple of 128
  }
}

// ---------------- compact + cast w1 rows ----------------
__global__ void compact_w1_kernel(const float* __restrict__ w1,
                                  const int* __restrict__ idx,
                                  const int* __restrict__ meta,
                                  unsigned short* __restrict__ w1c, int D) {
  int q = blockIdx.x * blockDim.x + threadIdx.x;
  int k = q >> 9;
  int d4 = (q & 511) << 2;
  int count = meta[0];
  ushort4 o = {0, 0, 0, 0};
  if (k < count) {
    int j = idx[k];
    float4 v = *(const float4*)(w1 + (long long)j * D + d4);
    o.x = f32_to_bf16_rn(v.x);
    o.y = f32_to_bf16_rn(v.y);
    o.z = f32_to_bf16_rn(v.z);
    o.w = f32_to_bf16_rn(v.w);
  }
  *(ushort4*)(w1c + (long long)k * D + d4) = o;
}

// ---------------- compact + cast w2 cols (ld 4096) ----------------
__global__ void compact_w2_kernel(const float* __restrict__ w2,
                                  const int* __restrict__ idx,
                                  const int* __restrict__ meta,
                                  unsigned short* __restrict__ w2c, int H) {
  int q = blockIdx.x * blockDim.x + threadIdx.x;
  int n = q >> 10;
  int k4 = (q & 1023) << 2;
  int count = meta[0];
  ushort4 o = {0, 0, 0, 0};
  const float* src = w2 + (long long)n * H;
#pragma unroll
  for (int u = 0; u < 4; ++u) {
    int k = k4 + u;
    unsigned short v = 0;
    if (k < count) v = f32_to_bf16_rn(src[idx[k]]);
    ((unsigned short*)&o)[u] = v;
  }
  *(ushort4*)(w2c + (long long)n * 4096 + k4) = o;
}

// ====== 128x64 tile, BK=64 pool GEMM: max FLOP/slot at 8 blocks/CU ==========
// Calibration across R1-R10: with a deep block queue, per-K-iter slot cost is
// ~700 cyc/CU regardless of schedule; perf = FLOP per slot. BK=64 doubles
// MFMA/slot (16/wave) while keeping 2048 blocks (8/CU queued, ~6 resident).
// Rows are 128B (8 granules); swizzle phys = logical ^ (row&7), inverse on
// gl_lds SOURCE column, linear LDS dest (both-sides rule); read toggles ^4kk.
template <int EPI>
__global__ __launch_bounds__(256, 4) void gemm_pool_kernel(
    const bf16_t* __restrict__ A, const bf16_t* __restrict__ B,
    void* __restrict__ Cout, long long ldA, long long ldB, long long ldC,
    int Kfix, int ncolFix, const int* __restrict__ meta) {
  const int kpad = meta[1];
  const int K = (EPI == 0) ? kpad : Kfix;               // GEMM2: K dynamic
  const int ncol = (EPI == 1) ? (kpad >> 6) : ncolFix;  // GEMM1: cols dynamic
  const int ntiles = ncol << 6;                         // nrow = 64

  __shared__ bf16_t As[128 * 64];  // 16 KB
  __shared__ bf16_t Bs[64 * 64];   // 8 KB

  const int tid = threadIdx.x;
  const int l = tid & 63;
  const int w = tid >> 6;
  const int wm = w >> 1;  // 0..1 : 64-row half
  const int wn = w & 1;   // 0..1 : 32-col half

  // staging: thread -> row (tid>>3) within a 32-row pass, phys granule tid&7;
  // source column pre-swizzled so LDS holds logical^ (row&7) at phys slot.
  const int srow = tid >> 3;                            // 0..31
  const int sg = ((tid & 7) ^ ((tid >> 3) & 7)) * 8;    // src col elems

  // fragment read: row = *+fr, phys granule gA ^ (4*kk), elems offset row*64
  const int fr = l & 15;
  const int gA = (l >> 4) ^ (l & 7);

  for (int tau = blockIdx.x; tau < ntiles; tau += gridDim.x) {
    const int row = tau & 63;
    const int col = tau >> 6;
    const long long brow = (long long)row * 128;
    const long long bcol = (long long)col * 64;

    const bf16_t* Ag = A + (brow + srow) * ldA + sg;
    const bf16_t* Bg = B + (bcol + srow) * ldB + sg;

    f32x4 acc[4][2];
#pragma unroll
    for (int m = 0; m < 4; ++m)
#pragma unroll
      for (int n = 0; n < 2; ++n) acc[m][n] = (f32x4){0.f, 0.f, 0.f, 0.f};

    for (int k0 = 0; k0 < K; k0 += 64) {
      // stage 24KB: A 4 passes of 32 rows, B 2 passes
      GLDS16(Ag + k0, &As[tid * 8]);
      GLDS16(Ag + 32 * ldA + k0, &As[2048 + tid * 8]);
      GLDS16(Ag + 64 * ldA + k0, &As[4096 + tid * 8]);
      GLDS16(Ag + 96 * ldA + k0, &As[6144 + tid * 8]);
      GLDS16(Bg + k0, &Bs[tid * 8]);
      GLDS16(Bg + 32 * ldB + k0, &Bs[2048 + tid * 8]);
      __syncthreads();
#pragma unroll
      for (int kk = 0; kk < 2; ++kk) {
        const int gp = (gA ^ (kk * 4)) * 8;  // phys granule elems
        bf16x8 af[4], bfr[2];
#pragma unroll
        for (int m = 0; m < 4; ++m)
          af[m] = *(const bf16x8*)(&As[(wm * 64 + m * 16 + fr) * 64 + gp]);
#pragma unroll
        for (int n = 0; n < 2; ++n)
          bfr[n] = *(const bf16x8*)(&Bs[(wn * 32 + n * 16 + fr) * 64 + gp]);
#pragma unroll
        for (int m = 0; m < 4; ++m)
#pragma unroll
          for (int n = 0; n < 2; ++n)
            acc[m][n] = __builtin_amdgcn_mfma_f32_16x16x32_bf16(
                af[m], bfr[n], acc[m][n], 0, 0, 0);
      }
      __syncthreads();
    }

    const int orow = wm * 64 + (l >> 4) * 4;
    const int ocol = wn * 32 + fr;
#pragma unroll
    for (int m = 0; m < 4; ++m)
#pragma unroll
      for (int n = 0; n < 2; ++n)
#pragma unroll
        for (int r = 0; r < 4; ++r) {
          long long rr = brow + orow + m * 16 + r;
          long long cc = bcol + ocol + n * 16;
          float v = acc[m][n][r];
          if (EPI == 1) {
            ((unsigned short*)Cout)[rr * ldC + cc] =
                f32_to_bf16_rn(gelu_exact(v));
          } else {
            ((float*)Cout)[rr * ldC + cc] = v;
          }
        }
  }
}

extern "C" void kernel_launch(void* const* d_in, const int* in_sizes, int n_in,
                              void* d_out, int out_size, void* d_ws,
                              size_t ws_size, hipStream_t stream) {
  const float* x = (const float*)d_in[0];
  const float* w1 = (const float*)d_in[1];
  const float* w2 = (const float*)d_in[2];
  const float* mask1 = (const float*)d_in[3];
  const float* mask2 = (const float*)d_in[4];
  float* out = (float*)d_out;

  const int D = 2048, H = 8192, M = 8192;
  const int KP = 4096;

  char* ws = (char*)d_ws;
  unsigned short* xb = (unsigned short*)ws;
  unsigned short* w1c = xb + (size_t)M * D;
  unsigned short* w2c = w1c + (size_t)KP * D;
  unsigned short* hb = w2c + (size_t)D * KP;
  int* idx = (int*)(hb + (size_t)M * KP);
  int* meta = idx + KP;

  build_idx_kernel<<<1, 1024, 0, stream>>>(mask1, mask2, idx, meta, H, D);

  {
    int n4 = (M * D) / 4;
    cast_x_kernel<<<n4 / 256, 256, 0, stream>>>(x, xb, n4);
  }
  {
    int nq = KP * (D / 4);
    compact_w1_kernel<<<nq / 256, 256, 0, stream>>>(w1, idx, meta, w1c, D);
  }
  {
    int nq = D * (KP / 4);
    compact_w2_kernel<<<nq / 256, 256, 0, stream>>>(w2, idx, meta, w2c, H);
  }

  const int POOL = 2048;  // 8 blocks/CU queued, ~6 resident (24KB LDS)

  // GEMM1: h[:, 0:kpad] = gelu(x @ w1c^T). K=2048 fixed; ncol = kpad/64 (dev)
  gemm_pool_kernel<1><<<POOL, 256, 0, stream>>>(
      (const bf16_t*)xb, (const bf16_t*)w1c, hb, (long long)D, (long long)D,
      (long long)KP, D, 0, meta);

  // GEMM2: out = h @ w2c^T. K = kpad (dev); ncol = 2048/64 = 32 fixed
  gemm_pool_kernel<0><<<POOL, 256, 0, stream>>>(
      (const bf16_t*)hb, (const bf16_t*)w2c, out, (long long)KP,
      (long long)KP, (long long)D, 0, 32, meta);
}

// Round 12
// 253.518 us; speedup vs baseline: 1.3128x; 1.0532x over previous
//
#include <hip/hip_runtime.h>
#include <hip/hip_bf16.h>

typedef __bf16 bf16_t;
typedef __bf16 bf16x8 __attribute__((ext_vector_type(8)));
typedef float f32x4 __attribute__((ext_vector_type(4)));

__device__ __forceinline__ unsigned short f32_to_bf16_rn(float f) {
  unsigned u = __float_as_uint(f);
  u += 0x7fffu + ((u >> 16) & 1u);
  return (unsigned short)(u >> 16);
}

__device__ __forceinline__ float gelu_exact(float x) {
  return 0.5f * x * (1.0f + erff(x * 0.7071067811865475f));
}

#define GLDS16(g, l)                                                          \
  __builtin_amdgcn_global_load_lds(                                           \
      (const __attribute__((address_space(1))) void*)(g),                     \
      (__attribute__((address_space(3))) void*)(l), 16, 0, 0)

// ---------------- cast x -> bf16 ----------------
__global__ void cast_x_kernel(const float* __restrict__ in,
                              unsigned short* __restrict__ out, int n4) {
  int i = blockIdx.x * blockDim.x + threadIdx.x;
  if (i >= n4) return;
  float4 v = ((const float4*)in)[i];
  ushort4 o;
  o.x = f32_to_bf16_rn(v.x);
  o.y = f32_to_bf16_rn(v.y);
  o.z = f32_to_bf16_rn(v.z);
  o.w = f32_to_bf16_rn(v.w);
  ((ushort4*)out)[i] = o;
}

// ---------------- build compacted index list (deterministic scan) ----------
__global__ void build_idx_kernel(const float* __restrict__ mask1,
                                 const float* __restrict__ mask2,
                                 int* __restrict__ idx, int* __restrict__ meta,
                                 int H, int D) {
  __shared__ int sums[1024];
  const int t = threadIdx.x;
  int flags[8];
  int tot = 0;
#pragma unroll
  for (int u = 0; u < 8; ++u) {
    int j = t * 8 + u;
    int f = (mask1[(long long)j * D] != 0.0f) && (mask2[j] != 0.0f);
    flags[u] = f;
    tot += f;
  }
  sums[t] = tot;
  __syncthreads();
  for (int off = 1; off < 1024; off <<= 1) {
    int v = (t >= off) ? sums[t - off] : 0;
    __syncthreads();
    sums[t] += v;
    __syncthreads();
  }
  int pos = sums[t] - tot;
#pragma unroll
  for (int u = 0; u < 8; ++u) {
    if (flags[u]) idx[pos++] = t * 8 + u;
  }
  if (t == 1023) {
    int count = sums[1023];
    meta[0] = count;
    meta[1] = (count + 127) & ~127;  // kpad: multiple of 128
  }
}

// ---------------- compact + cast w1 rows ----------------
__global__ void compact_w1_kernel(const float* __restrict__ w1,
                                  const int* __restrict__ idx,
                                  const int* __restrict__ meta,
                                  unsigned short* __restrict__ w1c, int D) {
  int q = blockIdx.x * blockDim.x + threadIdx.x;
  int k = q >> 9;
  int d4 = (q & 511) << 2;
  int count = meta[0];
  ushort4 o = {0, 0, 0, 0};
  if (k < count) {
    int j = idx[k];
    float4 v = *(const float4*)(w1 + (long long)j * D + d4);
    o.x = f32_to_bf16_rn(v.x);
    o.y = f32_to_bf16_rn(v.y);
    o.z = f32_to_bf16_rn(v.z);
    o.w = f32_to_bf16_rn(v.w);
  }
  *(ushort4*)(w1c + (long long)k * D + d4) = o;
}

// ---------------- compact + cast w2 cols (ld 4096) ----------------
__global__ void compact_w2_kernel(const float* __restrict__ w2,
                                  const int* __restrict__ idx,
                                  const int* __restrict__ meta,
                                  unsigned short* __restrict__ w2c, int H) {
  int q = blockIdx.x * blockDim.x + threadIdx.x;
  int n = q >> 10;
  int k4 = (q & 1023) << 2;
  int count = meta[0];
  ushort4 o = {0, 0, 0, 0};
  const float* src = w2 + (long long)n * H;
#pragma unroll
  for (int u = 0; u < 4; ++u) {
    int k = k4 + u;
    unsigned short v = 0;
    if (k < count) v = f32_to_bf16_rn(src[idx[k]]);
    ((unsigned short*)&o)[u] = v;
  }
  *(ushort4*)(w2c + (long long)n * 4096 + k4) = o;
}

// ====== 128x128 tile, BK=64 pool GEMM: halve bytes/FLOP on the L2 curve =====
// Measured law (R10/R11): slot = ~440 cyc + staged_KB * ~19 cyc/KB (33 TB/s
// aggregate L2). 128x128 stages 32KB per 2.1 MFLOP (vs 24KB/1.05M at 128x64).
// 4 waves (2x2), per-wave 64x64 out (acc 4x4), 32 MFMA/wave/slot. LDS 32KB
// single-buffered. Same proven swizzle: phys granule = logical ^ (row&7),
// inverse on gl_lds SOURCE col, linear dest; read gp = (gA ^ 4kk).
template <int EPI>
__global__ __launch_bounds__(256, 4) void gemm_pool_kernel(
    const bf16_t* __restrict__ A, const bf16_t* __restrict__ B,
    void* __restrict__ Cout, long long ldA, long long ldB, long long ldC,
    int Kfix, int ncolFix, const int* __restrict__ meta) {
  const int kpad = meta[1];
  const int K = (EPI == 0) ? kpad : Kfix;               // GEMM2: K dynamic
  const int ncol = (EPI == 1) ? (kpad >> 7) : ncolFix;  // GEMM1: cols dynamic
  const int ntiles = ncol << 6;                         // nrow = 64

  __shared__ bf16_t As[128 * 64];  // 16 KB
  __shared__ bf16_t Bs[128 * 64];  // 16 KB

  const int tid = threadIdx.x;
  const int l = tid & 63;
  const int w = tid >> 6;
  const int wm = w >> 1;  // 0..1 : 64-row half
  const int wn = w & 1;   // 0..1 : 64-col half

  // staging: thread -> row tid>>3 within 32-row pass, phys granule tid&7;
  // source column pre-swizzled by row&7 (pass stride 32 preserves row&7).
  const int srow = tid >> 3;                          // 0..31
  const int sg = ((tid & 7) ^ ((tid >> 3) & 7)) * 8;  // src col elems

  const int fr = l & 15;
  const int gA = (l >> 4) ^ (l & 7);

  for (int tau = blockIdx.x; tau < ntiles; tau += gridDim.x) {
    const int row = tau & 63;
    const int col = tau >> 6;
    const long long brow = (long long)row * 128;
    const long long bcol = (long long)col * 128;

    const bf16_t* Ag = A + (brow + srow) * ldA + sg;
    const bf16_t* Bg = B + (bcol + srow) * ldB + sg;

    f32x4 acc[4][4];
#pragma unroll
    for (int m = 0; m < 4; ++m)
#pragma unroll
      for (int n = 0; n < 4; ++n) acc[m][n] = (f32x4){0.f, 0.f, 0.f, 0.f};

    for (int k0 = 0; k0 < K; k0 += 64) {
      GLDS16(Ag + k0, &As[tid * 8]);
      GLDS16(Ag + 32 * ldA + k0, &As[2048 + tid * 8]);
      GLDS16(Ag + 64 * ldA + k0, &As[4096 + tid * 8]);
      GLDS16(Ag + 96 * ldA + k0, &As[6144 + tid * 8]);
      GLDS16(Bg + k0, &Bs[tid * 8]);
      GLDS16(Bg + 32 * ldB + k0, &Bs[2048 + tid * 8]);
      GLDS16(Bg + 64 * ldB + k0, &Bs[4096 + tid * 8]);
      GLDS16(Bg + 96 * ldB + k0, &Bs[6144 + tid * 8]);
      __syncthreads();
#pragma unroll
      for (int kk = 0; kk < 2; ++kk) {
        const int gp = (gA ^ (kk * 4)) * 8;
        bf16x8 af[4], bfr[4];
#pragma unroll
        for (int m = 0; m < 4; ++m)
          af[m] = *(const bf16x8*)(&As[(wm * 64 + m * 16 + fr) * 64 + gp]);
#pragma unroll
        for (int n = 0; n < 4; ++n)
          bfr[n] = *(const bf16x8*)(&Bs[(wn * 64 + n * 16 + fr) * 64 + gp]);
#pragma unroll
        for (int m = 0; m < 4; ++m)
#pragma unroll
          for (int n = 0; n < 4; ++n)
            acc[m][n] = __builtin_amdgcn_mfma_f32_16x16x32_bf16(
                af[m], bfr[n], acc[m][n], 0, 0, 0);
      }
      __syncthreads();
    }

    const int orow = wm * 64 + (l >> 4) * 4;
    const int ocol = wn * 64 + fr;
#pragma unroll
    for (int m = 0; m < 4; ++m)
#pragma unroll
      for (int n = 0; n < 4; ++n)
#pragma unroll
        for (int r = 0; r < 4; ++r) {
          long long rr = brow + orow + m * 16 + r;
          long long cc = bcol + ocol + n * 16;
          float v = acc[m][n][r];
          if (EPI == 1) {
            ((unsigned short*)Cout)[rr * ldC + cc] =
                f32_to_bf16_rn(gelu_exact(v));
          } else {
            ((float*)Cout)[rr * ldC + cc] = v;
          }
        }
  }
}

extern "C" void kernel_launch(void* const* d_in, const int* in_sizes, int n_in,
                              void* d_out, int out_size, void* d_ws,
                              size_t ws_size, hipStream_t stream) {
  const float* x = (const float*)d_in[0];
  const float* w1 = (const float*)d_in[1];
  const float* w2 = (const float*)d_in[2];
  const float* mask1 = (const float*)d_in[3];
  const float* mask2 = (const float*)d_in[4];
  float* out = (float*)d_out;

  const int D = 2048, H = 8192, M = 8192;
  const int KP = 4096;

  char* ws = (char*)d_ws;
  unsigned short* xb = (unsigned short*)ws;
  unsigned short* w1c = xb + (size_t)M * D;
  unsigned short* w2c = w1c + (size_t)KP * D;
  unsigned short* hb = w2c + (size_t)D * KP;
  int* idx = (int*)(hb + (size_t)M * KP);
  int* meta = idx + KP;

  build_idx_kernel<<<1, 1024, 0, stream>>>(mask1, mask2, idx, meta, H, D);

  {
    int n4 = (M * D) / 4;
    cast_x_kernel<<<n4 / 256, 256, 0, stream>>>(x, xb, n4);
  }
  {
    int nq = KP * (D / 4);
    compact_w1_kernel<<<nq / 256, 256, 0, stream>>>(w1, idx, meta, w1c, D);
  }
  {
    int nq = D * (KP / 4);
    compact_w2_kernel<<<nq / 256, 256, 0, stream>>>(w2, idx, meta, w2c, H);
  }

  // GEMM1: h[:, 0:kpad] = gelu(x @ w1c^T). K=2048 fixed; ncol = kpad/128 (dev)
  // 2048 blocks covers worst-case ntiles (KP/128*64); extras exit immediately.
  gemm_pool_kernel<1><<<2048, 256, 0, stream>>>(
      (const bf16_t*)xb, (const bf16_t*)w1c, hb, (long long)D, (long long)D,
      (long long)KP, D, 0, meta);

  // GEMM2: out = h @ w2c^T. K = kpad (dev); ncol = 2048/128 = 16 fixed
  gemm_pool_kernel<0><<<1024, 256, 0, stream>>>(
      (const bf16_t*)hb, (const bf16_t*)w2c, out, (long long)KP,
      (long long)KP, (long long)D, 0, 16, meta);
}